// Round 1
// baseline (106.717 us; speedup 1.0000x reference)
//
#include <hip/hip_runtime.h>
#include <math.h>

#define NN     8192
#define FDIM   64
#define EDGES  262144
#define BATCH  2
#define ALPHA  0.2f

#define ROWCAP 128        // per-src slot capacity (Poisson(32): max deg ~70)
#define CNTPAD 16         // 1 counter per 64B line: avoids cross-XCD line ping-pong

// ---- ws layout ----
#define OFF_WH    0u          // float[B*N*64]      4 MB
#define OFF_S1    4194304u    // float[B*N]         64 KB
#define OFF_S2    4259840u    // float[B*N]         64 KB
#define OFF_CNT   4325376u    // int[8192*16]       512 KB (padded row counters)
#define OFF_ROWS  4849664u    // uint2[8192*128]    8 MB   (row-major edge slots)

// K1: proven LDS-staged GEMM (Wh, s1, s2) + direct row scatter via global
// atomics. No hist/scan/offsT — the deterministic chunk layout is gone;
// dedupe (max-e wins) and masking (val==0) are order-independent, so an
// arbitrary within-row order is safe.
__global__ __launch_bounds__(1024) void stage1_kernel(
    const float* __restrict__ h, const float* __restrict__ W,
    const float* __restrict__ a, const int* __restrict__ ei,
    const float* __restrict__ ew,
    float* __restrict__ Wh, float* __restrict__ s1g, float* __restrict__ s2g,
    int* __restrict__ cnt, uint2* __restrict__ rows) {
  __shared__ float sW[64 * 65];   // pad: bank (lane+k)%32, 2-way = free
  __shared__ float sH[64 * 64];
  int tid = threadIdx.x, lane = tid & 63, w = tid >> 6;
  int blk = blockIdx.x;

  // issue edge loads early (coalesced); scatter happens at kernel end so the
  // atomic latency overlaps the GEMM instead of stalling a barrier drain
  int e = blk * 1024 + tid;
  int s = ei[e], d = ei[EDGES + e];
  float wgt = ew[e];

  // ---- Wh = h@W^T, s1, s2 (64 rows per block, LDS-staged) ----
  for (int i = tid; i < 4096; i += 1024) sW[(i >> 6) * 65 + (i & 63)] = W[i];
  int rr = lane >> 4, c4 = lane & 15;
  int nn0 = blk * 64 + w * 4;                 // [0, B*N)
  *(float4*)(sH + (w * 4 + rr) * 64 + c4 * 4) =
      *(const float4*)(h + (size_t)(nn0 + rr) * 64 + c4 * 4);
  __syncthreads();

  const float* wp = sW + lane * 65;
  const float* hp = sH + (w * 4) * 64;
  float acc[4] = {0.f, 0.f, 0.f, 0.f};
#pragma unroll 8
  for (int k = 0; k < 64; ++k) {
    float wv = wp[k];
    acc[0] += hp[k] * wv;
    acc[1] += hp[64 + k] * wv;
    acc[2] += hp[128 + k] * wv;
    acc[3] += hp[192 + k] * wv;
  }
  float a1 = a[lane], a2 = a[64 + lane];
#pragma unroll
  for (int r = 0; r < 4; ++r) {
    int nn = nn0 + r;
    Wh[(size_t)nn * 64 + lane] = acc[r];
    float p1 = acc[r] * a1, p2 = acc[r] * a2;
#pragma unroll
    for (int off = 32; off; off >>= 1) {
      p1 += __shfl_xor(p1, off, 64);
      p2 += __shfl_xor(p2, off, 64);
    }
    if (lane == 0) { s1g[nn] = p1; s2g[nn] = p2; }
  }

  // ---- row scatter: slot = src*ROWCAP + rank ----
  int rank = atomicAdd(&cnt[s * CNTPAD], 1);
  if (rank < ROWCAP)
    rows[s * ROWCAP + rank] =
        make_uint2(((unsigned)e << 13) | (unsigned)d, __float_as_uint(wgt));
}

// K2: barrier-free. 512 blocks (B x 256 groups) x 1024 thr; each wave owns 2
// src rows of its batch: coalesced row load, bitmap dup-detect (fastpath
// skips the O(deg) shuffle dedupe), masked softmax, 4-lane-per-edge float4
// gather from L2-resident Wh. No __syncthreads anywhere.
__global__ __launch_bounds__(1024) void stage2_kernel(
    const float* __restrict__ s1g, const float* __restrict__ s2g,
    const int* __restrict__ cnt, const uint2* __restrict__ rows,
    const float* __restrict__ Wh, float* __restrict__ out) {
  __shared__ unsigned bmap[16 * 256];          // per-wave 8192-bit dst bitmap
  __shared__ uint2 sE[16 * ROWCAP];            // per-wave {dst, p} stash
  int tid = threadIdx.x, lane = tid & 63, w = tid >> 6;   // 16 waves
  int blk = blockIdx.x;
  int xcd = blk & 7;
  int b = xcd >> 2;                            // XCD 0-3: batch 0, 4-7: batch 1
  int g = (blk >> 3) * 4 + (xcd & 3);          // [0, 256)
  const float* s2b = s2g + b * NN;
  const float* Whb = Wh + (size_t)b * NN * FDIM;
  unsigned* mywords = bmap + w * 256;
  uint2* myE = sE + w * ROWCAP;
  int fg = lane & 15, es = lane >> 4;

  for (int q = 0; q < 2; ++q) {
    int n = g * 32 + w * 2 + q;                // src row [0, 8192)
    int deg = cnt[n * CNTPAD];
    if (deg > ROWCAP) deg = ROWCAP;
    float4 r4 = make_float4(0.f, 0.f, 0.f, 0.f);
    if (deg > 0) {
      float s1v = s1g[b * NN + n];
      bool two = deg > 64;
      // ---- coalesced row load ----
      unsigned k0 = 0, k1 = 0; float w0 = 0.f, w1 = 0.f;
      if (lane < deg) {
        uint2 E = rows[n * ROWCAP + lane];
        k0 = E.x; w0 = __uint_as_float(E.y);
      }
      if (two && lane + 64 < deg) {
        uint2 E = rows[n * ROWCAP + 64 + lane];
        k1 = E.x; w1 = __uint_as_float(E.y);
      }
      // ---- per-edge value ----
      float v0 = 0.f, v1 = 0.f;
      if (lane < deg) {
        int dst = (int)(k0 & 0x1FFFu);
        float x = s1v + s2b[dst];
        v0 = (x > 0.f ? x : ALPHA * x) * w0;
      }
      if (two && lane + 64 < deg) {
        int dst = (int)(k1 & 0x1FFFu);
        float x = s1v + s2b[dst];
        v1 = (x > 0.f ? x : ALPHA * x) * w1;
      }
      // ---- dedupe: max-e key wins (deterministic, order-independent) ----
      if (!two) {
#pragma unroll
        for (int u = 0; u < 4; ++u) mywords[u * 64 + lane] = 0u;
        bool dup = false;
        if (lane < deg) {
          int dst = (int)(k0 & 0x1FFFu);
          unsigned old = atomicOr(&mywords[dst >> 5], 1u << (dst & 31));
          dup = (old >> (dst & 31)) & 1u;
        }
        if (__ballot(dup) != 0ull) {           // ~13% of rows
          for (int j = 0; j < deg; ++j) {
            unsigned q2 = __shfl(k0, j, 64);
            if ((((q2 ^ k0) & 0x1FFFu) == 0u) & (q2 > k0)) v0 = 0.f;
          }
        }
      } else {                                 // deg in (64,128] — rare
        for (int j = 0; j < 64; ++j) {
          unsigned q2 = __shfl(k0, j, 64);
          if ((((q2 ^ k0) & 0x1FFFu) == 0u) & (q2 > k0)) v0 = 0.f;
          if ((((q2 ^ k1) & 0x1FFFu) == 0u) & (q2 > k1)) v1 = 0.f;
        }
        for (int j = 0; j < deg - 64; ++j) {
          unsigned q2 = __shfl(k1, j, 64);
          if ((((q2 ^ k0) & 0x1FFFu) == 0u) & (q2 > k0)) v0 = 0.f;
          if ((((q2 ^ k1) & 0x1FFFu) == 0u) & (q2 > k1)) v1 = 0.f;
        }
      }
      // ---- masked softmax (val==0 == masked, faithful to reference) ----
      float m = fmaxf((v0 != 0.f) ? v0 : -INFINITY,
                      (two && v1 != 0.f) ? v1 : -INFINITY);
#pragma unroll
      for (int off = 32; off; off >>= 1) m = fmaxf(m, __shfl_xor(m, off, 64));
      float p0 = (v0 != 0.f) ? expf(v0 - m) : 0.f;
      float p1 = (two && v1 != 0.f) ? expf(v1 - m) : 0.f;
      float sum = p0 + p1;
#pragma unroll
      for (int off = 32; off; off >>= 1) sum += __shfl_xor(sum, off, 64);
      float inv = (sum > 0.f) ? 1.f / sum : 0.f;
      // ---- stash {dst, p} (wave-internal LDS: DS ops in-order, no barrier) ----
      if (lane < deg) myE[lane] = make_uint2(k0 & 0x1FFFu, __float_as_uint(p0));
      if (two && lane + 64 < deg)
        myE[64 + lane] = make_uint2(k1 & 0x1FFFu, __float_as_uint(p1));
      // ---- 4-lane-per-edge gather: 8 float4 loads in flight (32 edges) ----
      float4 acc = make_float4(0.f, 0.f, 0.f, 0.f);
      for (int kk = 0; kk < deg; kk += 32) {
        float4 vv[8]; float pp[8];
#pragma unroll
        for (int u = 0; u < 8; ++u) {
          int k = kk + u * 4 + es;
          int kc = k < deg ? k : deg - 1;      // clamp: stays a valid entry
          uint2 E = myE[kc];
          pp[u] = (k < deg) ? __uint_as_float(E.y) : 0.f;
          vv[u] = *((const float4*)(Whb + (size_t)E.x * 64) + fg);
        }
#pragma unroll
        for (int u = 0; u < 8; ++u) {
          acc.x += pp[u] * vv[u].x; acc.y += pp[u] * vv[u].y;
          acc.z += pp[u] * vv[u].z; acc.w += pp[u] * vv[u].w;
        }
      }
#pragma unroll
      for (int off = 16; off <= 32; off <<= 1) {
        acc.x += __shfl_xor(acc.x, off, 64);
        acc.y += __shfl_xor(acc.y, off, 64);
        acc.z += __shfl_xor(acc.z, off, 64);
        acc.w += __shfl_xor(acc.w, off, 64);
      }
      r4.x = acc.x * inv; r4.y = acc.y * inv; r4.z = acc.z * inv; r4.w = acc.w * inv;
    }
    if (es == 0) {                             // lanes 0..15 store 64 floats
      r4.x = r4.x > 0.f ? r4.x : expm1f(r4.x);
      r4.y = r4.y > 0.f ? r4.y : expm1f(r4.y);
      r4.z = r4.z > 0.f ? r4.z : expm1f(r4.z);
      r4.w = r4.w > 0.f ? r4.w : expm1f(r4.w);
      *((float4*)(out + ((size_t)b * NN + n) * 64) + fg) = r4;
    }
  }
}

extern "C" void kernel_launch(void* const* d_in, const int* in_sizes, int n_in,
                              void* d_out, int out_size, void* d_ws, size_t ws_size,
                              hipStream_t stream) {
  const float* h  = (const float*)d_in[0];
  const float* W  = (const float*)d_in[1];
  const float* a  = (const float*)d_in[2];
  const int*   ei = (const int*)d_in[3];
  const float* ew = (const float*)d_in[4];
  float* out = (float*)d_out;

  char* ws = (char*)d_ws;
  float* Wh   = (float*)(ws + OFF_WH);
  float* s1   = (float*)(ws + OFF_S1);
  float* s2   = (float*)(ws + OFF_S2);
  int*   cnt  = (int*)(ws + OFF_CNT);
  uint2* rows = (uint2*)(ws + OFF_ROWS);

  hipMemsetAsync(cnt, 0, NN * CNTPAD * sizeof(int), stream);
  stage1_kernel<<<256, 1024, 0, stream>>>(h, W, a, ei, ew, Wh, s1, s2, cnt, rows);
  stage2_kernel<<<BATCH * 256, 1024, 0, stream>>>(s1, s2, cnt, rows, Wh, out);
}